// Round 1
// baseline (110.822 us; speedup 1.0000x reference)
//
#include <hip/hip_runtime.h>
#include <math.h>

namespace {
constexpr int B = 64, A = 5, H = 52, W = 52, T = 50;
constexpr int HW = H * W;        // 2704
constexpr int N = A * HW;        // 13520
constexpr int CH2 = 2 * A * HW;  // 27040 (per-batch xy/wh/weight span)
constexpr float POS_THRESH_F = 0.6f;
constexpr float EPS_F = 1e-5f;
// Conservative decision band: ~2.7e-5 relative ~ 100+ ulp, vastly wider than
// the ~2 ulp rounding difference between (tb+ta)*(1+c) and tb*(1+c)+ta*(1+c),
// and than the reference's iou-division rounding. Anything inside the band
// reruns the exact IEEE loop.
constexpr float C_BAND = 2.6667e-5f;
constexpr float K_HI = 1.0f + C_BAND;
constexpr float K_LO = 1.0f - C_BAND;

// d_out layout: t_xy, t_wh, t_xywh_weight, t_o_obj, t_o_noobj, t_label (flat, f32)
constexpr long O_XY = 0;
constexpr long O_WH = (long)B * CH2;
constexpr long O_WT = 2L * B * CH2;
constexpr long O_OBJ = 3L * B * CH2;
constexpr long O_NOOBJ = O_OBJ + (long)B * N;
constexpr long O_LABEL = O_NOOBJ + (long)B * N;
}  // namespace

// Kernel 1: per predicted box, "any IoU > 0.6?" over 50 truths -> t_o_noobj
// mask; also writes the base values of all six outputs.
// Division-free threshold test: iou>0.6 <=> ov > 0.375*(barea+ta). The
// pre-scaled forms tbHi+taHi[t] (= 0.375*(barea+ta)*(1+c)) and tbLo+taLo[t]
// give a 13-VALU-op inner iteration:
//   anyHi: clearly above threshold -> hit
//   anyLo && !anyHi: some truth inside the band -> exact IEEE replay
// so boundary decisions stay bit-identical to the reference.
__global__ __launch_bounds__(256) void region_k1(
    const float* __restrict__ xy, const float* __restrict__ wh,
    const float* __restrict__ obj, const float* __restrict__ truth,
    const float* __restrict__ biases, float* __restrict__ out) {
#pragma clang fp contract(off)
  __shared__ float4 s_box[T];   // {tl, tt, tr, tb}
  __shared__ float2 s_thr[T];   // {0.375*ta*K_HI, 0.375*ta*K_LO}
  __shared__ float s_ta[T];     // exact tw*th for the fallback loop
  const int b = blockIdx.y;
  const int tid = threadIdx.x;
  if (tid < T) {
    const float* t5 = truth + ((long)b * T + tid) * 5;
    const float tx = t5[0], ty = t5[1], tw = t5[2], th = t5[3];
    s_box[tid] = make_float4(tx - tw * 0.5f, ty - th * 0.5f,
                             tx + tw * 0.5f, ty + th * 0.5f);
    const float ta = tw * th;
    s_ta[tid] = ta;
    const float t375 = 0.375f * ta;
    s_thr[tid] = make_float2(t375 * K_HI, t375 * K_LO);
  }
  __syncthreads();
  const int n = blockIdx.x * 256 + tid;
  if (n >= N) return;
  const int a = n / HW;
  const int r = n - a * HW;
  const int h = r / W;
  const int w = r - h * W;
  const long pb = (long)b * CH2;
  const long ix = pb + (long)a * HW + r;  // channel a (x / w-part)
  const long iy = ix + (long)A * HW;      // channel a+A (y / h-part)
  const float x = xy[ix], y = xy[iy];
  const float wx = wh[ix], wyv = wh[iy];
  const long io = (long)b * N + n;
  const float objv = obj[io];
  // box center/size — mirror reference f32 op order exactly
  const float bx = (x + (float)w) / (float)W;
  const float by = (y + (float)h) / (float)H;
  const float bw = expf(wx) * biases[2 * a] / (float)W;
  const float bh = expf(wyv) * biases[2 * a + 1] / (float)H;
  const float bl = bx - bw * 0.5f, brr = bx + bw * 0.5f;
  const float bt = by - bh * 0.5f, bbt = by + bh * 0.5f;
  const float barea = bw * bh;
  const float tb375 = 0.375f * barea;
  const float tbHi = tb375 * K_HI;
  const float tbLo = tb375 * K_LO;
  bool anyHi = false, anyLo = false;
#pragma unroll 10
  for (int t = 0; t < T; ++t) {
    const float4 b4 = s_box[t];
    const float2 th2 = s_thr[t];
    float ow = fminf(brr, b4.z) - fmaxf(bl, b4.x);
    float oh = fminf(bbt, b4.w) - fmaxf(bt, b4.y);
    ow = fmaxf(ow, 0.0f);
    oh = fmaxf(oh, 0.0f);
    const float ov = ow * oh;
    anyHi = anyHi || (ov > tbHi + th2.x);
    anyLo = anyLo || (ov > tbLo + th2.y);
  }
  bool hit = anyHi;
  if (anyLo && !anyHi) {
    // exact fallback — identical op sequence to the reference
    float m = -INFINITY;
    for (int t = 0; t < T; ++t) {
      const float4 b4 = s_box[t];
      float ow = fminf(brr, b4.z) - fmaxf(bl, b4.x);
      float oh = fminf(bbt, b4.w) - fmaxf(bt, b4.y);
      ow = fmaxf(ow, 0.0f);
      oh = fmaxf(oh, 0.0f);
      const float ov = ow * oh;
      const float iou = ov / ((barea + s_ta[t]) - ov);
      m = fmaxf(m, iou);
    }
    hit = m > POS_THRESH_F;
  }
  out[O_NOOBJ + io] = hit ? objv : 0.0f;
  out[O_OBJ + io] = objv;
  out[O_LABEL + io] = -1.0f;
  out[O_XY + ix] = x;
  out[O_XY + iy] = y;
  out[O_WH + ix] = wx;
  out[O_WH + iy] = wyv;
  out[O_WT + ix] = 0.0f;
  out[O_WT + iy] = 0.0f;
}

// Kernel 2: per-batch truth scatters with exact JAX .at[] semantics:
//  - negative index (-1) wraps to the last element (JAX normalizes before drop)
//  - lin1 with channel 2*tn+A >= 2A is genuinely OOB -> dropped
//  - duplicate targets: last write (ascending t, lin0-scatter before
//    lin1-scatter) wins — enforced via parallel "am I the last writer to my
//    address in the sequence?" checks instead of the old serial replay.
__global__ __launch_bounds__(128) void region_k2(
    const float* __restrict__ xy, const float* __restrict__ wh,
    const float* __restrict__ obj, const float* __restrict__ truth,
    const float* __restrict__ biases, float* __restrict__ out) {
#pragma clang fp contract(off)
  __shared__ float s_vx[T], s_vy[T], s_vw[T], s_vh[T], s_vwt[T];
  __shared__ float s_vobj[T], s_vnoobj[T], s_cls[T];
  __shared__ int s_cell[T], s_eff[T], s_lin0[T], s_lin1[T], s_tn[T], s_win[T];
  __shared__ int s_tgt2[2 * T];  // xy/wh/wt-plane scatter sequence (-2 = drop)
  __shared__ int s_tgtO[T];      // obj-plane scatter sequence
  const int b = blockIdx.x;
  const int t = threadIdx.x;
  if (t < T) {
    const float* t5 = truth + ((long)b * T + t) * 5;
    const float tx = t5[0], ty = t5[1], tw = t5[2], th = t5[3];
    s_cls[t] = t5[4];
    int ti = (int)(tx * (float)W);  // trunc, matches astype(int32)
    int tj = (int)(ty * (float)H);
    int tn = 0;
    float best = -INFINITY;
    for (int aa = 0; aa < A; ++aa) {
      const float bwa = biases[2 * aa] / (float)W;
      const float bha = biases[2 * aa + 1] / (float)H;
      const float num = fminf(tw, bwa) * fminf(th, bha);
      const float den = fmaxf(tw, bwa) * fmaxf(th, bha) + EPS_F;
      const float rr = num / den;
      if (rr > best) { best = rr; tn = aa; }  // first-max, like jnp.argmax
    }
    if (tw <= EPS_F || th <= EPS_F) { ti = -1; tj = -1; tn = -1; }
    const bool valid = ti >= 0;
    const int cell = valid ? (tn * H + tj) * W + ti : -1;
    s_cell[t] = cell;
    s_eff[t] = valid ? cell : (N - 1);  // -1 wraps to N-1 in winner scatter
    const int nc = tn < 0 ? 0 : tn, jc = tj < 0 ? 0 : tj, ic = ti < 0 ? 0 : ti;
    s_tn[t] = tn;
    s_lin0[t] = (2 * tn * H + tj) * W + ti;        // only used when win
    s_lin1[t] = ((2 * tn + A) * H + tj) * W + ti;  // only used when win
    s_vx[t] = tx * (float)W - (float)ic;
    s_vy[t] = ty * (float)H - (float)jc;
    s_vw[t] = logf(fmaxf(tw * (float)W / biases[2 * nc], 1e-12f));
    s_vh[t] = logf(fmaxf(th * (float)H / biases[2 * nc + 1], 1e-12f));
    s_vwt[t] = 2.0f - tw * th;  // COORD_SCALE = 1
    // v_obj = IoU of predicted box at (nc,jc,ic) vs this truth (RESCORE)
    const long rr2 = (long)nc * HW + (long)jc * W + ic;
    const long pb = (long)b * CH2;
    const float x = xy[pb + rr2], y = xy[pb + (long)A * HW + rr2];
    const float wx = wh[pb + rr2], wyv = wh[pb + (long)A * HW + rr2];
    s_vnoobj[t] = obj[(long)b * N + rr2];
    const float bx = (x + (float)ic) / (float)W;
    const float by = (y + (float)jc) / (float)H;
    const float bw = expf(wx) * biases[2 * nc] / (float)W;
    const float bh = expf(wyv) * biases[2 * nc + 1] / (float)H;
    float ow = fminf(bx + bw * 0.5f, tx + tw * 0.5f) -
               fmaxf(bx - bw * 0.5f, tx - tw * 0.5f);
    float oh = fminf(by + bh * 0.5f, ty + th * 0.5f) -
               fmaxf(by - bh * 0.5f, ty - th * 0.5f);
    ow = fmaxf(ow, 0.0f);
    oh = fmaxf(oh, 0.0f);
    const float ov = ow * oh;
    s_vobj[t] = ov / (((bw * bh) + tw * th) - ov);
  }
  __syncthreads();
  if (t < T) {
    int winf = 0;
    if (s_cell[t] >= 0) {  // valid
      winf = 1;
      for (int u = t + 1; u < T; ++u)
        if (s_eff[u] == s_cell[t]) { winf = 0; break; }  // higher t wins
    }
    s_win[t] = winf;
  }
  __syncthreads();
  if (t < T) {
    const int J = CH2 - 1;  // wrapped target of index -1 in 2A*H*W space
    int tgt0, tgt1;
    if (s_win[t]) {
      tgt0 = s_lin0[t];
      tgt1 = (2 * s_tn[t] + A < 2 * A) ? s_lin1[t] : -2;  // OOB -> dropped
    } else {
      tgt0 = J;  // -1 wraps
      tgt1 = J;
    }
    s_tgt2[t] = tgt0;
    s_tgt2[T + t] = tgt1;
    s_tgtO[t] = s_win[t] ? s_cell[t] : (N - 1);
  }
  __syncthreads();
  // xy/wh/wt planes: one 2T-item sequence, identical targets for all three
  if (t < 2 * T) {
    const int tg = s_tgt2[t];
    if (tg >= 0) {
      bool alive = true;
      for (int j = t + 1; j < 2 * T; ++j) alive &= (s_tgt2[j] != tg);
      if (alive) {
        const int u = (t < T) ? t : (t - T);
        const float vxy = (t < T) ? s_vx[u] : s_vy[u];
        const float vwh = (t < T) ? s_vw[u] : s_vh[u];
        out[O_XY + (long)b * CH2 + tg] = vxy;
        out[O_WH + (long)b * CH2 + tg] = vwh;
        out[O_WT + (long)b * CH2 + tg] = s_vwt[u];
      }
    }
  }
  // obj planes: one T-item sequence, identical targets for all three
  if (t < T) {
    const int tg = s_tgtO[t];
    bool alive = true;
    for (int j = t + 1; j < T; ++j) alive &= (s_tgtO[j] != tg);
    if (alive) {
      out[O_OBJ + (long)b * N + tg] = s_vobj[t];
      out[O_NOOBJ + (long)b * N + tg] = s_vnoobj[t];
      out[O_LABEL + (long)b * N + tg] = s_cls[t];
    }
  }
}

extern "C" void kernel_launch(void* const* d_in, const int* in_sizes, int n_in,
                              void* d_out, int out_size, void* d_ws,
                              size_t ws_size, hipStream_t stream) {
  const float* xy = (const float*)d_in[0];
  const float* wh = (const float*)d_in[1];
  const float* obj = (const float*)d_in[2];
  const float* truth = (const float*)d_in[3];
  const float* biases = (const float*)d_in[4];
  float* out = (float*)d_out;
  dim3 g1((N + 255) / 256, B);
  region_k1<<<g1, 256, 0, stream>>>(xy, wh, obj, truth, biases, out);
  region_k2<<<B, 128, 0, stream>>>(xy, wh, obj, truth, biases, out);
}